// Round 11
// baseline (358.537 us; speedup 1.0000x reference)
//
#include <hip/hip_runtime.h>

// ---------------------------------------------------------------------------
// MultiHeadAttention: B=4, S=2048, D=1024, H=16, Dh=64. FP32 I/O.
// cvt (weights+mask only) -> merged QKV GEMM reading f32 activations
// DIRECTLY (reg-staged f32->bf16 cvt, T14 issue-early/write-late; kills the
// 144MB q/k/v bf16 round-trip) -> flash attention (unchanged R9/R10 v10) ->
// out GEMM (unchanged R10).
// ---------------------------------------------------------------------------

typedef __bf16 bf16x8 __attribute__((ext_vector_type(8)));
typedef __bf16 bf16x4 __attribute__((ext_vector_type(4)));
typedef float  f32x4  __attribute__((ext_vector_type(4)));

#define LOG2E 1.44269504088896340736f
#define SCALE_Q (0.125f * LOG2E)      // 1/sqrt(64) * log2(e), folded into Q
#define MBIAS_L2 (-1.44269504e9f)     // -1e9 * log2(e)
#define MFMA16(a, b, c) __builtin_amdgcn_mfma_f32_16x16x32_bf16(a, b, c, 0, 0, 0)

__device__ inline unsigned short f2bf(float f) {  // RNE f32 -> bf16 bits
  unsigned int u = __float_as_uint(f);
  u = u + 0x7FFF + ((u >> 16) & 1);
  return (unsigned short)(u >> 16);
}
__device__ inline void gload16(const void* g, void* l) {  // 16B global->LDS DMA
  __builtin_amdgcn_global_load_lds(
      (const __attribute__((address_space(1))) void*)g,
      (__attribute__((address_space(3))) void*)l, 16, 0, 0);
}
__device__ inline bf16x8 cvt8(const float* p) {  // 8 f32 -> bf16x8
  float4 a = *(const float4*)p, b = *(const float4*)(p + 4);
  bf16x8 v;
  v[0] = (__bf16)a.x; v[1] = (__bf16)a.y; v[2] = (__bf16)a.z; v[3] = (__bf16)a.w;
  v[4] = (__bf16)b.x; v[5] = (__bf16)b.y; v[6] = (__bf16)b.z; v[7] = (__bf16)b.w;
  return v;
}
__device__ inline bf16x8 cvt8r(const float4& a, const float4& b) {  // regs -> bf16x8
  bf16x8 v;
  v[0] = (__bf16)a.x; v[1] = (__bf16)a.y; v[2] = (__bf16)a.z; v[3] = (__bf16)a.w;
  v[4] = (__bf16)b.x; v[5] = (__bf16)b.y; v[6] = (__bf16)b.z; v[7] = (__bf16)b.w;
  return v;
}

// ---------------------------------------------------------------------------
// cvt_all: weights f32->bf16 (4 jobs) + mask int -> f32 bias table (job 4).
// grid (512, 5), 256 thr. q/k/v conversion is now fused into gemm_qkv.
// ---------------------------------------------------------------------------
struct CvtJob { const float* s; unsigned short* d; int n8; };
struct CvtJobs { CvtJob j[5]; };
__global__ void cvt_all(CvtJobs J) {
  CvtJob jb = J.j[blockIdx.y];
  int i = blockIdx.x * 256 + threadIdx.x;
  if (blockIdx.y == 4) {  // mask -> bias (8192 ints, int4/thread)
    if (i < jb.n8) {
      int4 m = ((const int4*)jb.s)[i];
      float4 o;
      o.x = m.x ? 0.f : MBIAS_L2;
      o.y = m.y ? 0.f : MBIAS_L2;
      o.z = m.z ? 0.f : MBIAS_L2;
      o.w = m.w ? 0.f : MBIAS_L2;
      ((float4*)jb.d)[i] = o;
    }
    return;
  }
  if (i < jb.n8) *(bf16x8*)(jb.d + (size_t)i * 8) = cvt8(jb.s + (size_t)i * 8);
}

// ---------------------------------------------------------------------------
// gemm_qkv: merged Q/K/V projections from FP32 activations, grid (8, 64, 3).
// A staging is reg-based (T14 split): issue 4x global_load_dwordx4 early,
// compute current buffer's MFMAs while they fly, then cvt->ds_write_b128
// just before the barrier. W stays bf16 global_load_lds DMA (converted once
// by cvt_all). Numerics identical to the old cvt pass (same RNE casts).
// z in {0:Q,1:K} swapped orientation; z==2 (V) writes Vt[(b*16+h)*64+d]
// [perm(s)] (key-permuted for attn's single-b128 PV fragments).
// XCD swizzle (R7) + single-barrier dbuf (R8) + (256,3) (R10).
// ---------------------------------------------------------------------------
struct ProjJob { const float* A; const unsigned short* W;
                 const float* bias; unsigned short* out; float scale; };
struct ProjJobs { ProjJob j[3]; };

__global__ __launch_bounds__(256, 3) void gemm_qkv(ProjJobs J) {
  __shared__ __align__(16) unsigned short Al[2][128 * 32];
  __shared__ __align__(16) unsigned short Wl[2][128 * 32];
  const int z = blockIdx.z;
  const ProjJob jb = J.j[z];
  const int tid = threadIdx.x, lane = tid & 63, w = tid >> 6;
  const int lid = lane & 15, lg = lane >> 4;
  // XCD swizzle: bijective over 512 blocks/z; z*512 preserves wg&7.
  const int lin = blockIdx.x + 8 * (int)blockIdx.y;
  const int xcd = lin & 7, j = lin >> 3;
  const int c0 = (j & 7) * 128;
  const int t0 = ((j >> 3) * 8 + xcd) * 128;
  const int wm = (w & 1) * 64, wn = (w >> 1) * 64;

  f32x4 acc[4][4];
#pragma unroll
  for (int i = 0; i < 4; i++)
#pragma unroll
    for (int jj = 0; jj < 4; jj++) acc[i][jj] = (f32x4){0.f, 0.f, 0.f, 0.f};

  // A (f32): issue loads into regs; write (cvt) later.
  auto stage_load = [&](int kt, float4 (&ar)[2][2]) {
#pragma unroll
    for (int i = 0; i < 2; i++) {
      int c = i * 256 + tid, r = c >> 2, ko = (c & 3) * 8;
      const float* ap = jb.A + (size_t)(t0 + r) * 1024 + kt + ko;
      ar[i][0] = *(const float4*)ap;
      ar[i][1] = *(const float4*)(ap + 4);
    }
  };
  auto stage_write = [&](int bi, float4 (&ar)[2][2]) {
#pragma unroll
    for (int i = 0; i < 2; i++) {
      int c = i * 256 + tid;
      *(bf16x8*)(&Al[bi][c * 8]) = cvt8r(ar[i][0], ar[i][1]);
    }
  };
  // W (bf16): direct DMA, stays in flight until the barrier.
  auto stage_W = [&](int bi, int kt) {
#pragma unroll
    for (int i = 0; i < 2; i++) {
      int c = i * 256 + tid, r = c >> 2, ko = (c & 3) * 8;
      gload16(jb.W + (size_t)(c0 + r) * 1024 + kt + ko, &Wl[bi][c * 8]);
    }
  };
  auto compute = [&](int bi) {
    const unsigned short* Ml = (z == 2) ? Al[bi] : Wl[bi];
    const unsigned short* Nl = (z == 2) ? Wl[bi] : Al[bi];
    bf16x8 mf[4], nf[4];
#pragma unroll
    for (int mi = 0; mi < 4; mi++)
      mf[mi] = *(const bf16x8*)(&Ml[(wm + mi * 16 + lid) * 32 + lg * 8]);
#pragma unroll
    for (int ni = 0; ni < 4; ni++)
      nf[ni] = *(const bf16x8*)(&Nl[(wn + ni * 16 + lid) * 32 + lg * 8]);
#pragma unroll
    for (int mi = 0; mi < 4; mi++)
#pragma unroll
      for (int ni = 0; ni < 4; ni++)
        acc[mi][ni] = MFMA16(mf[mi], nf[ni], acc[mi][ni]);
  };

  float4 arA[2][2], arB[2][2];
  stage_load(0, arA);
  stage_W(0, 0);
  stage_write(0, arA);
  __syncthreads();

  for (int kt = 0; kt < 1024; kt += 64) {
    stage_load(kt + 32, arB);          // issue early (A f32 -> regs)
    stage_W(1, kt + 32);               // DMA, lands at the barrier
    compute(0);                        // loads fly under the MFMAs
    stage_write(1, arB);               // vmcnt-waits only the A loads
    __syncthreads();
    if (kt + 64 < 1024) {
      stage_load(kt + 64, arA);
      stage_W(0, kt + 64);
    }
    compute(1);
    if (kt + 64 < 1024) stage_write(0, arA);
    __syncthreads();
  }

  if (z < 2) {
    const float scale = jb.scale;
#pragma unroll
    for (int mi = 0; mi < 4; mi++) {
      int colb = c0 + wm + mi * 16 + lg * 4;
      float4 b4 = *(const float4*)(&jb.bias[colb]);
#pragma unroll
      for (int ni = 0; ni < 4; ni++) {
        int token = t0 + wn + ni * 16 + lid;
        ushort4 st;
        st.x = f2bf((acc[mi][ni][0] + b4.x) * scale);
        st.y = f2bf((acc[mi][ni][1] + b4.y) * scale);
        st.z = f2bf((acc[mi][ni][2] + b4.z) * scale);
        st.w = f2bf((acc[mi][ni][3] + b4.w) * scale);
        *(ushort4*)(&jb.out[(size_t)token * 1024 + colb]) = st;
      }
    }
  } else {
    const int b = t0 >> 11;  // whole 128-token tile lies in one batch
#pragma unroll
    for (int ni = 0; ni < 4; ni++) {
      int col = c0 + wn + ni * 16 + lid;
      int h = col >> 6, d = col & 63;
      float bv = jb.bias[col];
#pragma unroll
      for (int mi = 0; mi < 4; mi++) {
        int s = (t0 & 2047) + wm + mi * 16 + lg * 4;  // 4-aligned key group
        // permuted key position (bijective per 32-block)
        int sp = (s & ~31) | (((s >> 2) & 3) << 3) | (((s >> 4) & 1) << 2);
        ushort4 st;
        st.x = f2bf(acc[mi][ni][0] + bv);
        st.y = f2bf(acc[mi][ni][1] + bv);
        st.z = f2bf(acc[mi][ni][2] + bv);
        st.w = f2bf(acc[mi][ni][3] + bv);
        *(ushort4*)(&jb.out[(size_t)((b * 16 + h) * 64 + d) * 2048 + sp]) = st;
      }
    }
  }
}

// ---------------------------------------------------------------------------
// gemm_o: f32 C[token][col] = A_bf16 @ W_bf16^T + bias. 64x128 tiles,
// grid (8,128) = 4 blk/CU, XCD swizzle + dbuf (unchanged R10).
// ---------------------------------------------------------------------------
__global__ __launch_bounds__(256, 4) void gemm_o(
    const unsigned short* __restrict__ A, const unsigned short* __restrict__ W,
    const float* __restrict__ bias, float* __restrict__ C) {
  __shared__ __align__(16) unsigned short Al[2][64 * 32];
  __shared__ __align__(16) unsigned short Wl[2][128 * 32];
  const int tid = threadIdx.x, lane = tid & 63, w = tid >> 6;
  const int lid = lane & 15, lg = lane >> 4;
  const int lin = blockIdx.x + 8 * (int)blockIdx.y;  // grid (8,128) = 1024
  const int xcd = lin & 7, j = lin >> 3;             // j in 0..127
  const int c0 = (j & 7) * 128;
  const int t0 = ((j >> 3) * 8 + xcd) * 64;
  const int wc = (w & 1) * 64, wt = (w >> 1) * 32;
  f32x4 acc[4][2];
#pragma unroll
  for (int i = 0; i < 4; i++)
#pragma unroll
    for (int jj = 0; jj < 2; jj++) acc[i][jj] = (f32x4){0.f, 0.f, 0.f, 0.f};

  auto stage = [&](int bi, int kt) {
#pragma unroll
    for (int i = 0; i < 2; i++) {
      int c = i * 256 + tid, r = c >> 2, ko = (c & 3) * 8;
      gload16(W + (size_t)(c0 + r) * 1024 + kt + ko, &Wl[bi][c * 8]);
    }
    {
      int c = tid, r = c >> 2, ko = (c & 3) * 8;
      gload16(A + (size_t)(t0 + r) * 1024 + kt + ko, &Al[bi][c * 8]);
    }
  };
  auto compute = [&](int bi) {
    bf16x8 aw[4], bt[2];
#pragma unroll
    for (int mi = 0; mi < 4; mi++)
      aw[mi] = *(const bf16x8*)(&Wl[bi][(wc + mi * 16 + lid) * 32 + lg * 8]);
#pragma unroll
    for (int ni = 0; ni < 2; ni++)
      bt[ni] = *(const bf16x8*)(&Al[bi][(wt + ni * 16 + lid) * 32 + lg * 8]);
#pragma unroll
    for (int mi = 0; mi < 4; mi++)
#pragma unroll
      for (int ni = 0; ni < 2; ni++)
        acc[mi][ni] = MFMA16(aw[mi], bt[ni], acc[mi][ni]);
  };

  stage(0, 0);
  __syncthreads();
  for (int kt = 0; kt < 1024; kt += 64) {
    stage(1, kt + 32);
    compute(0);
    __syncthreads();
    if (kt + 64 < 1024) stage(0, kt + 64);
    compute(1);
    __syncthreads();
  }
#pragma unroll
  for (int mi = 0; mi < 4; mi++) {
    int colb = c0 + wc + mi * 16 + lg * 4;
    float4 b4 = *(const float4*)(&bias[colb]);
#pragma unroll
    for (int ni = 0; ni < 2; ni++) {
      int token = t0 + wt + ni * 16 + lid;
      float4 st;
      st.x = acc[mi][ni][0] + b4.x;
      st.y = acc[mi][ni][1] + b4.y;
      st.z = acc[mi][ni][2] + b4.z;
      st.w = acc[mi][ni][3] + b4.w;
      *(float4*)(&C[(size_t)token * 1024 + colb]) = st;
    }
  }
}

// ---------------------------------------------------------------------------
// Flash attention v10 (unchanged from R9: 78.5us, 0 bank conflicts).
// ---------------------------------------------------------------------------
__global__ __launch_bounds__(256, 4) void attn(
    const unsigned short* __restrict__ Qp,   // (B*S, 1024), pre-scaled
    const unsigned short* __restrict__ Kp,   // (B*S, 1024)
    const unsigned short* __restrict__ Vt,   // (B*H, 64, 2048) key-permuted
    const float* __restrict__ mbias,         // (B, 2048) f32 bias table
    unsigned short* __restrict__ ctx) {      // (B*S, 1024)
  __shared__ __align__(16) unsigned short Klds[2][64 * 64];  // [key][d], XOR-swz
  __shared__ __align__(16) unsigned short Vlds[2][64 * 64];  // [d][key'], XOR-swz

  const int tid = threadIdx.x, lane = tid & 63, w = tid >> 6;
  const int lid = lane & 15, lg = lane >> 4;
  // XCD shard: one (b,h)'s 16 q-blocks stay on one XCD's L2.
  const int wg = blockIdx.x + (int)(gridDim.x) * blockIdx.y;
  const int xcd = wg & 7, idx = wg >> 3;
  const int bh = (xcd << 3) | (idx >> 4);
  const int q0 = (idx & 15) * 128;
  const int b = bh >> 4, h = bh & 15;
  const int wq = w * 32;
  const int x7 = lid & 7;  // XOR swizzle key (row&7 == lid&7 for all reads)

  const unsigned short* Kg = Kp + (size_t)(b * 2048) * 1024 + h * 64;
  const unsigned short* Vg = Vt + (size_t)bh * 64 * 2048;
  const float* mg = mbias + b * 2048;

  // Q fragments (B-operand of S^T): lane holds Q[q=qt*16+lid][d=ks*32+lg*8..]
  bf16x8 qf[2][2];
#pragma unroll
  for (int qt = 0; qt < 2; qt++)
#pragma unroll
    for (int ks = 0; ks < 2; ks++) {
      int qrow = b * 2048 + q0 + wq + qt * 16 + lid;
      qf[qt][ks] = *(const bf16x8*)(Qp + (size_t)qrow * 1024 + h * 64 + ks * 32 + lg * 8);
    }

  f32x4 Ot[4][2];  // O^T[d=dt*16+lg*4+r][q=qt*16+lid]
#pragma unroll
  for (int dt = 0; dt < 4; dt++)
#pragma unroll
    for (int qt = 0; qt < 2; qt++) Ot[dt][qt] = (f32x4){0.f, 0.f, 0.f, 0.f};
  f32x4 acc_l[2] = {(f32x4){0.f, 0.f, 0.f, 0.f}, (f32x4){0.f, 0.f, 0.f, 0.f}};
  bf16x8 ones8;
#pragma unroll
  for (int i = 0; i < 8; i++) ones8[i] = (__bf16)1.0f;

  // stage one 64-key tile (K 64x64, V^T 64x64) into the given buffer
  auto stage_kv = [&](unsigned short* Kl, unsigned short* Vl, int k0) {
#pragma unroll
    for (int i = 0; i < 2; i++) {
      int c = i * 256 + tid, r = c >> 3, gsw = (c & 7) ^ (r & 7);
      gload16(Kg + (size_t)(k0 + r) * 1024 + gsw * 8, Kl + c * 8);
    }
#pragma unroll
    for (int i = 0; i < 2; i++) {
      int c = i * 256 + tid, d = c >> 3, gsw = (c & 7) ^ (d & 7);
      gload16(Vg + (size_t)d * 2048 + k0 + gsw * 8, Vl + c * 8);
    }
  };

  // one 64-key tile: shared-K QK^T (both q-halves per K fragment) ->
  // softmax -> ones-rowsum + PV (single-b128 V fragments).
  auto compute_tile = [&](const unsigned short* Kl, const unsigned short* Vl, int kt) {
    const float* mrow = mg + kt * 64;
    f32x4 accS[4][2];
#pragma unroll
    for (int mt = 0; mt < 4; mt++) {
      f32x4 mb4 = *(const f32x4*)(&mrow[mt * 16 + lg * 4]);
      accS[mt][0] = mb4;
      accS[mt][1] = mb4;
    }
    __builtin_amdgcn_s_setprio(1);
#pragma unroll
    for (int ks = 0; ks < 2; ks++) {
      int koff = ((ks * 4 + lg) ^ x7) * 8;  // swizzled granule within row
#pragma unroll
      for (int mt = 0; mt < 4; mt++) {
        bf16x8 a = *(const bf16x8*)(&Kl[(mt * 16 + lid) * 64 + koff]);
        accS[mt][0] = MFMA16(a, qf[0][ks], accS[mt][0]);
        accS[mt][1] = MFMA16(a, qf[1][ks], accS[mt][1]);
      }
    }
    __builtin_amdgcn_s_setprio(0);

    // fixed-max softmax: p = exp2(score); P packed into B-frags pb[c][qt]
    bf16x8 pb[2][2];
#pragma unroll
    for (int qt = 0; qt < 2; qt++)
#pragma unroll
      for (int mt = 0; mt < 4; mt++) {
        int half = (mt & 1) * 4;
#pragma unroll
        for (int r = 0; r < 4; r++) {
          float p = __builtin_amdgcn_exp2f(accS[mt][qt][r]);
          pb[mt >> 1][qt][half + r] = (__bf16)p;
        }
      }

    __builtin_amdgcn_s_setprio(1);
    // row-sum l += ones . P^T (key permutation irrelevant for a sum)
#pragma unroll
    for (int c = 0; c < 2; c++)
#pragma unroll
      for (int qt = 0; qt < 2; qt++)
        acc_l[qt] = MFMA16(ones8, pb[c][qt], acc_l[qt]);

    // O^T += V^T . P^T; producer-permuted V: one b128 granule per (c).
#pragma unroll
    for (int c = 0; c < 2; c++) {
      int goff = (((c * 4 + lg) ^ x7)) * 8;
#pragma unroll
      for (int dt = 0; dt < 4; dt++) {
        bf16x8 av = *(const bf16x8*)(&Vl[(dt * 16 + lid) * 64 + goff]);
        Ot[dt][0] = MFMA16(av, pb[c][0], Ot[dt][0]);
        Ot[dt][1] = MFMA16(av, pb[c][1], Ot[dt][1]);
      }
    }
    __builtin_amdgcn_s_setprio(0);
  };

  stage_kv(&Klds[0][0], &Vlds[0][0], 0);
  __syncthreads();  // drains vmcnt(0): buf0 ready

  // x2-unrolled: prefetch issued BEFORE compute, drained by the
  // end-of-tile barrier (implicit vmcnt(0)+lgkmcnt(0)).
  for (int kt = 0; kt < 32; kt += 2) {
    stage_kv(&Klds[1][0], &Vlds[1][0], (kt + 1) * 64);
    compute_tile(&Klds[0][0], &Vlds[0][0], kt);
    __syncthreads();
    if (kt + 2 < 32) stage_kv(&Klds[0][0], &Vlds[0][0], (kt + 2) * 64);
    compute_tile(&Klds[1][0], &Vlds[1][0], kt + 1);
    __syncthreads();
  }

  // epilogue: ctx[q][h*64+d] = O^T/l ; d packed x4 -> 8B stores
#pragma unroll
  for (int qt = 0; qt < 2; qt++) {
    float inv = 1.0f / acc_l[qt][0];
    int qrow = b * 2048 + q0 + wq + qt * 16 + lid;
#pragma unroll
    for (int dt = 0; dt < 4; dt++) {
      ushort4 st;
      st.x = f2bf(Ot[dt][qt][0] * inv);
      st.y = f2bf(Ot[dt][qt][1] * inv);
      st.z = f2bf(Ot[dt][qt][2] * inv);
      st.w = f2bf(Ot[dt][qt][3] * inv);
      *(ushort4*)(&ctx[(size_t)qrow * 1024 + h * 64 + dt * 16 + lg * 4]) = st;
    }
  }
}

// ---------------------------------------------------------------------------
extern "C" void kernel_launch(void* const* d_in, const int* in_sizes, int n_in,
                              void* d_out, int out_size, void* d_ws, size_t ws_size,
                              hipStream_t stream) {
  const float* q  = (const float*)d_in[0];
  const float* k  = (const float*)d_in[1];
  const float* v  = (const float*)d_in[2];
  const int*   mk = (const int*)d_in[3];
  const float* Wq = (const float*)d_in[4];
  const float* bq = (const float*)d_in[5];
  const float* Wk = (const float*)d_in[6];
  const float* bk = (const float*)d_in[7];
  const float* Wv = (const float*)d_in[8];
  const float* bv = (const float*)d_in[9];
  const float* Wo = (const float*)d_in[10];
  const float* bo = (const float*)d_in[11];

  const size_t NTOK = (size_t)8192 * 1024;   // elements per activation tensor
  const size_t NW = (size_t)1024 * 1024;     // elements per weight

  unsigned short* ctx = (unsigned short*)d_ws;
  unsigned short* Qp  = ctx + NTOK;
  unsigned short* Kp  = Qp + NTOK;
  unsigned short* Vt  = Kp + NTOK;
  unsigned short* Wqb = Vt + NTOK;
  unsigned short* Wkb = Wqb + NW;
  unsigned short* Wvb = Wkb + NW;
  unsigned short* Wob = Wvb + NW;
  float*          mbg = (float*)(Wob + NW);  // (B,2048) f32 bias table, 32KB

  CvtJobs J;
  J.j[0] = {Wq, Wqb, (int)(NW / 8)};
  J.j[1] = {Wk, Wkb, (int)(NW / 8)};
  J.j[2] = {Wv, Wvb, (int)(NW / 8)};
  J.j[3] = {Wo, Wob, (int)(NW / 8)};
  J.j[4] = {(const float*)mk, (unsigned short*)mbg, 2048};  // mask -> bias
  cvt_all<<<dim3(512, 5), 256, 0, stream>>>(J);

  ProjJobs P;
  P.j[0] = {q, Wqb, bq, Qp, SCALE_Q};
  P.j[1] = {k, Wkb, bk, Kp, 1.0f};
  P.j[2] = {v, Wvb, bv, Vt, 1.0f};
  gemm_qkv<<<dim3(8, 64, 3), 256, 0, stream>>>(P);

  attn<<<dim3(16, 64), 256, 0, stream>>>(Qp, Kp, Vt, mbg, ctx);
  gemm_o<<<dim3(8, 128), 256, 0, stream>>>(ctx, Wob, bo, (float*)d_out);
}